// Round 6
// baseline (340.359 us; speedup 1.0000x reference)
//
#include <hip/hip_runtime.h>

// SAGE_Net: 2-layer GraphSAGE, N=100k, E=1.6M, 128->128->64, fp32.
// R15: latency-pipeline the gathers + consolidate launches.
//  - Phase A (fused): col vectors for all 8 nodes prefetched upfront;
//    node i+1's first 16 gather rows issued (deg>=16 uniform guard, no
//    waste) before node i's reduce/epilogue -> miss queue stays full
//    during compute tails. Node loop fully unrolled (static reg indexing).
//  - agg_out: 1-deep col prefetch in the 16-edge loop.
//  - Launches 8->6: prep+bcount merged (disjoint block ranges); bscan
//    dropped -- bscatter/bfinal recompute the <=512-bucket scan locally
//    in LDS; bcur zero-init folded into the bcnt memset (contiguous).
// Numerics bit-identical to R14 (same loads, same add order).

typedef unsigned int uint32;
typedef short bf16x4 __attribute__((ext_vector_type(4)));
typedef short bf16x8 __attribute__((ext_vector_type(8)));
typedef float f32x16 __attribute__((ext_vector_type(16)));
typedef float f32x2 __attribute__((ext_vector_type(2)));

#define PSTR 264  // LDS plane stride in shorts (32*8 + 8 pad; 528B)

__device__ __forceinline__ uint32 pack_bf16_rne(float a, float b) {
    uint32 ua = __float_as_uint(a);
    uint32 ub = __float_as_uint(b);
    uint32 ra = (ua + 0x7fffu + ((ua >> 16) & 1u)) >> 16;
    uint32 rb = (ub + 0x7fffu + ((ub >> 16) & 1u)) >> 16;
    return ra | (rb << 16);
}
__device__ __forceinline__ float bf_lo(uint32 v) { return __uint_as_float(v << 16); }
__device__ __forceinline__ float bf_hi(uint32 v) { return __uint_as_float(v & 0xffff0000u); }

__device__ __forceinline__ short rne16(float v, float* back) {
    uint32 u = __float_as_uint(v);
    uint32 r = (u + 0x7fffu + ((u >> 16) & 1u)) >> 16;
    *back = __uint_as_float(r << 16);
    return (short)r;
}

// ---- prep (x -> xb bf16; weights -> hi/lo planes) + bcount, one kernel ----
__global__ void k_prepcount(const float* __restrict__ x, uint32* __restrict__ xb,
                            long n4,
                            const float* __restrict__ W1l, const float* __restrict__ W1r,
                            const float* __restrict__ W2l, const float* __restrict__ W2r,
                            short* __restrict__ W1pH, short* __restrict__ W1pL,
                            short* __restrict__ W2pH, short* __restrict__ W2pL,
                            const int* __restrict__ ei, int E, int NB,
                            int* __restrict__ bucket_cnt, int prep_blocks) {
    __shared__ int hist[512];
    int t = threadIdx.x;
    if ((int)blockIdx.x >= prep_blocks) {
        // ---- bcount section (256 blocks) ----
        int bb = (int)blockIdx.x - prep_blocks;
        for (int i = t; i < NB; i += 256) hist[i] = 0;
        __syncthreads();
        int stride = 256 * 256;
        for (int e = bb * 256 + t; e < E; e += stride)
            atomicAdd(&hist[ei[E + e] >> 8], 1);
        __syncthreads();
        for (int i = t; i < NB; i += 256) {
            int c = hist[i];
            if (c) atomicAdd(&bucket_cnt[i], c);
        }
        return;
    }
    long i = (long)blockIdx.x * blockDim.x + t;
    float back;
    if (i < n4) {
        float4 v = ((const float4*)x)[i];
        short h0 = rne16(v.x, &back);
        short h1 = rne16(v.y, &back);
        short h2 = rne16(v.z, &back);
        short h3 = rne16(v.w, &back);
        uint2 o;
        o.x = (uint32)(unsigned short)h0 | ((uint32)(unsigned short)h1 << 16);
        o.y = (uint32)(unsigned short)h2 | ((uint32)(unsigned short)h3 << 16);
        ((uint2*)xb)[i] = o;
        return;
    }
    int i2 = (int)(i - n4);
    if (i2 < 32768) {
        int j = i2 >> 8, k = i2 & 255;
        float v = (k < 128) ? W1l[j * 128 + k] : W1r[j * 128 + k - 128];
        float hb;
        short hs = rne16(v, &hb);
        short ls = rne16(v - hb, &back);
        int idx = (k >> 3) * 1024 + j * 8 + (k & 7);
        W1pH[idx] = hs;
        W1pL[idx] = ls;
    } else if (i2 < 32768 + 16384) {
        int i3 = i2 - 32768;
        int j = i3 >> 7, k = i3 & 127;
        float v = (j < 64) ? W2l[j * 128 + k] : W2r[(j - 64) * 128 + k];
        float hb;
        short hs = rne16(v, &hb);
        short ls = rne16(v - hb, &back);
        int idx = (k >> 3) * 1024 + j * 8 + (k & 7);
        W2pH[idx] = hs;
        W2pL[idx] = ls;
    }
}

// ---- bscatter with local bucket scan (NB <= 512; this problem: 391) ----
__global__ void k_bscatter(const int* __restrict__ ei, int E, int NB,
                           const int* __restrict__ bcnt, int* __restrict__ bcur,
                           uint32* __restrict__ eb) {
    __shared__ int sc[512];
    __shared__ int hist[512];
    __shared__ int basev[512];
    int t = threadIdx.x;
    int c0 = (t < NB) ? bcnt[t] : 0;
    int c1 = (t + 256 < NB) ? bcnt[t + 256] : 0;
    sc[t] = c0;
    sc[t + 256] = c1;
    hist[t] = 0;
    hist[t + 256] = 0;
    __syncthreads();
    for (int o = 1; o < 512; o <<= 1) {
        int a0 = (t >= o) ? sc[t - o] : 0;
        int a1 = (t + 256 >= o) ? sc[t + 256 - o] : 0;
        __syncthreads();
        sc[t] += a0;
        sc[t + 256] += a1;
        __syncthreads();
    }
    int stride = gridDim.x * 256;
    for (int e = blockIdx.x * 256 + t; e < E; e += stride)
        atomicAdd(&hist[ei[E + e] >> 8], 1);
    __syncthreads();
    {
        int c = hist[t];
        if (t < NB) basev[t] = (sc[t] - c0) + (c ? atomicAdd(&bcur[t], c) : 0);
        hist[t] = 0;
        int i1 = t + 256;
        int c2 = hist[i1];
        if (i1 < NB) basev[i1] = (sc[i1] - c1) + (c2 ? atomicAdd(&bcur[i1], c2) : 0);
        hist[i1] = 0;
    }
    __syncthreads();
    for (int e = blockIdx.x * 256 + t; e < E; e += stride) {
        int d = ei[E + e];
        int b = d >> 8;
        int r = atomicAdd(&hist[b], 1);
        eb[basev[b] + r] = ((uint32)(d & 255) << 24) | (uint32)ei[e];
    }
}

// ---- bfinal with local bucket scan ----
__global__ void k_bfinal(const uint32* __restrict__ eb,
                         const int* __restrict__ bcnt,
                         int* __restrict__ row_ptr, int* __restrict__ col,
                         int N, int E, int NB) {
    __shared__ int sc[512];
    __shared__ int deg[256];
    __shared__ int scn[256];
    __shared__ int cur[256];
    int b = blockIdx.x;
    int t = threadIdx.x;
    sc[t] = (t < NB) ? bcnt[t] : 0;
    sc[t + 256] = (t + 256 < NB) ? bcnt[t + 256] : 0;
    deg[t] = 0;
    __syncthreads();
    for (int o = 1; o < 512; o <<= 1) {
        int a0 = (t >= o) ? sc[t - o] : 0;
        int a1 = (t + 256 >= o) ? sc[t + 256 - o] : 0;
        __syncthreads();
        sc[t] += a0;
        sc[t + 256] += a1;
        __syncthreads();
    }
    int beg = (b > 0) ? sc[b - 1] : 0;
    int end = sc[b];
    for (int e = beg + t; e < end; e += 256)
        atomicAdd(&deg[eb[e] >> 24], 1);
    __syncthreads();
    int v = deg[t];
    scn[t] = v;
    __syncthreads();
    for (int o = 1; o < 256; o <<= 1) {
        int u = (t >= o) ? scn[t - o] : 0;
        __syncthreads();
        scn[t] += u;
        __syncthreads();
    }
    int ex = scn[t] - v;
    int node = b * 256 + t;
    if (node < N) row_ptr[node] = beg + ex;
    if (b == gridDim.x - 1 && t == 0) row_ptr[N] = E;
    cur[t] = ex;
    __syncthreads();
    for (int e = beg + t; e < end; e += 256) {
        uint32 u = eb[e];
        int r = atomicAdd(&cur[u >> 24], 1);
        col[beg + r] = (int)(u & 0xFFFFFFu);
    }
}

// ---- fused gather-mean + 2x MFMA GEMM. Block = 32 nodes, 4 waves. ----

__global__ __launch_bounds__(256, 4) void k_fused(
        const int* __restrict__ rp, const int* __restrict__ col,
        const uint32* __restrict__ xb,
        const short* __restrict__ W1pH, const short* __restrict__ W1pL,
        const short* __restrict__ W2pH, const short* __restrict__ W2pL,
        const float* __restrict__ b1, const float* __restrict__ b2,
        unsigned short* __restrict__ hl, float* __restrict__ hr, int N) {
    __shared__ short smH[16 * PSTR];  // mean hi planes; reused for h hi
    __shared__ short smL[16 * PSTR];  // mean lo planes; reused for h lo
    int t = threadIdx.x;
    int w = t >> 6, lane = t & 63;
    int g = lane >> 4, f = lane & 15;
    int node0 = blockIdx.x * 32;
    const uint4* xb4 = (const uint4*)xb;  // row = 16 uint4

    // phase A: gather-mean for 8 nodes/wave, software-pipelined.
    int base = node0 + 8 * w;
    int rpi = base + lane;
    if (rpi > N) rpi = N;
    int rpv = rp[rpi];

    // col vectors for all 8 nodes' first 16 edges, issued upfront.
    // Overshoot reads land <=60B past col inside the workspace (safe,
    // never dereferenced unless the guard below proves them valid).
    uint4 cvv[8];
#pragma unroll
    for (int i = 0; i < 8; i++) {
        int bi = __shfl(rpv, i);
        cvv[i] = *(const uint4*)(col + bi + 4 * g);
    }
    // first-row prefetch for node 0 (deg>=16 only: zero wasted traffic)
    uint4 p0 = {}, p1 = {}, p2 = {}, p3 = {};
    {
        int b0 = __builtin_amdgcn_readfirstlane(__shfl(rpv, 0));
        int e0 = __builtin_amdgcn_readfirstlane(__shfl(rpv, 1));
        if (e0 - b0 >= 16) {
            uint4 cvp = cvv[0];
            p0 = xb4[(size_t)cvp.x * 16 + f];
            p1 = xb4[(size_t)cvp.y * 16 + f];
            p2 = xb4[(size_t)cvp.z * 16 + f];
            p3 = xb4[(size_t)cvp.w * 16 + f];
        }
    }

#pragma unroll
    for (int i = 0; i < 8; i++) {
        int lr = 8 * w + i;
        int beg = __builtin_amdgcn_readfirstlane(__shfl(rpv, i));
        int end = __builtin_amdgcn_readfirstlane(__shfl(rpv, i + 1));
        f32x2 sA[4];
#pragma unroll
        for (int j = 0; j < 4; j++) sA[j] = (f32x2){0.f, 0.f};

#define ACC_RAW(v)                                                      \
    { sA[0] += (f32x2){bf_lo(v.x), __uint_as_float(v.x)};               \
      sA[1] += (f32x2){bf_lo(v.y), __uint_as_float(v.y)};               \
      sA[2] += (f32x2){bf_lo(v.z), __uint_as_float(v.z)};               \
      sA[3] += (f32x2){bf_lo(v.w), __uint_as_float(v.w)}; }

        int e = beg;
        bool has16 = (e + 16 <= end);
        uint4 v0, v1, v2, v3;
        if (has16) { v0 = p0; v1 = p1; v2 = p2; v3 = p3; }  // waits on pN
        // issue NEXT node's first-row prefetch before this node's compute
        if (i < 7) {
            int nb = __builtin_amdgcn_readfirstlane(__shfl(rpv, i + 1));
            int ne = __builtin_amdgcn_readfirstlane(__shfl(rpv, i + 2));
            if (ne - nb >= 16) {
                uint4 cvp = cvv[i + 1];
                p0 = xb4[(size_t)cvp.x * 16 + f];
                p1 = xb4[(size_t)cvp.y * 16 + f];
                p2 = xb4[(size_t)cvp.z * 16 + f];
                p3 = xb4[(size_t)cvp.w * 16 + f];
            }
        }
        if (has16) {
            uint4 cv = *(const uint4*)(col + e + 16 + 4 * g);  // ws-safe
            ACC_RAW(v0); ACC_RAW(v1); ACC_RAW(v2); ACC_RAW(v3);
            e += 16;
            while (e + 16 <= end) {  // deg>=32: rare
                uint4 w0 = xb4[(size_t)cv.x * 16 + f];
                uint4 w1 = xb4[(size_t)cv.y * 16 + f];
                uint4 w2 = xb4[(size_t)cv.z * 16 + f];
                uint4 w3 = xb4[(size_t)cv.w * 16 + f];
                uint4 cvn = *(const uint4*)(col + e + 16 + 4 * g);
                ACC_RAW(w0); ACC_RAW(w1); ACC_RAW(w2); ACC_RAW(w3);
                e += 16;
                cv = cvn;
            }
        }
        for (; e + 8 <= end; e += 8) {
            uint2 cv2 = *(const uint2*)(col + e + 2 * g);
            uint4 u0 = xb4[(size_t)cv2.x * 16 + f];
            uint4 u1 = xb4[(size_t)cv2.y * 16 + f];
            ACC_RAW(u0); ACC_RAW(u1);
        }
        int rem = end - e;
        if (2 * g < rem) {
            uint4 u0 = xb4[(size_t)col[e + 2 * g] * 16 + f];
            ACC_RAW(u0);
        }
        if (2 * g + 1 < rem) {
            uint4 u0 = xb4[(size_t)col[e + 2 * g + 1] * 16 + f];
            ACC_RAW(u0);
        }
#undef ACC_RAW
#pragma unroll
        for (int p = 0; p < 4; p++) {
            sA[p].x += __shfl_xor(sA[p].x, 16);
            sA[p].y += __shfl_xor(sA[p].y, 16);
            sA[p].x += __shfl_xor(sA[p].x, 32);
            sA[p].y += __shfl_xor(sA[p].y, 32);
        }
        // distributed epilogue: lane (g,f) -> plane f, features 2g,2g+1
        float inv = 1.0f / (float)max(end - beg, 1);
        float m0 = sA[g].x * inv, m1 = sA[g].y * inv;
        float b_;
        short h0 = rne16(m0, &b_);
        float bk0 = b_;
        short l0 = rne16(m0 - bk0, &b_);
        short h1 = rne16(m1, &b_);
        float bk1 = b_;
        short l1 = rne16(m1 - bk1, &b_);
        uint32 H = (uint32)(unsigned short)h0 | ((uint32)(unsigned short)h1 << 16);
        uint32 L = (uint32)(unsigned short)l0 | ((uint32)(unsigned short)l1 << 16);
        *(uint32*)&smH[f * PSTR + lr * 8 + 2 * g] = H;
        *(uint32*)&smL[f * PSTR + lr * 8 + 2 * g] = L;
    }
    __syncthreads();

    // phase B: GEMM1 (mean hi/lo from LDS + x hi direct from xb), tile jt=w
    int m = lane & 31, hh = lane >> 5;
    int mynode = node0 + m;
    const short* xbs = (const short*)xb;  // row = 128 shorts (feature order)
    f32x16 acc;
#pragma unroll
    for (int r = 0; r < 16; r++) acc[r] = 0.f;
#pragma unroll
    for (int kc = 0; kc < 8; kc++) {
        int c = 2 * kc + hh;
        bf16x8 bH = *(const bf16x8*)&smH[c * PSTR + m * 8];
        bf16x8 bL = *(const bf16x8*)&smL[c * PSTR + m * 8];
        bf16x8 xH = *(const bf16x8*)(xbs + (size_t)mynode * 128 + c * 8);
        bf16x8 aH1 = *(const bf16x8*)(W1pH + c * 1024 + (32 * w + m) * 8);
        bf16x8 aL1 = *(const bf16x8*)(W1pL + c * 1024 + (32 * w + m) * 8);
        bf16x8 aH2 = *(const bf16x8*)(W1pH + (16 + c) * 1024 + (32 * w + m) * 8);
        bf16x8 aL2 = *(const bf16x8*)(W1pL + (16 + c) * 1024 + (32 * w + m) * 8);
        acc = __builtin_amdgcn_mfma_f32_32x32x16_bf16(aH1, bH, acc, 0, 0, 0);
        acc = __builtin_amdgcn_mfma_f32_32x32x16_bf16(aL1, bH, acc, 0, 0, 0);
        acc = __builtin_amdgcn_mfma_f32_32x32x16_bf16(aH1, bL, acc, 0, 0, 0);
        acc = __builtin_amdgcn_mfma_f32_32x32x16_bf16(aH2, xH, acc, 0, 0, 0);
        acc = __builtin_amdgcn_mfma_f32_32x32x16_bf16(aL2, xH, acc, 0, 0, 0);
    }

    // epilogue 1: relu + b1 -> h (hi/lo) in regs
    uint2 oh[4], ol[4];
#pragma unroll
    for (int rg = 0; rg < 4; rg++) {
        int j0 = 32 * w + 8 * rg + 4 * hh;
        float4 bv = *(const float4*)(b1 + j0);
        float bb[4] = {bv.x, bv.y, bv.z, bv.w};
        short hs[4], ls[4];
#pragma unroll
        for (int q = 0; q < 4; q++) {
            float v = fmaxf(acc[4 * rg + q] + bb[q], 0.f);
            float back;
            hs[q] = rne16(v, &back);
            ls[q] = rne16(v - back, &back);
        }
        oh[rg].x = (uint32)(unsigned short)hs[0] | ((uint32)(unsigned short)hs[1] << 16);
        oh[rg].y = (uint32)(unsigned short)hs[2] | ((uint32)(unsigned short)hs[3] << 16);
        ol[rg].x = (uint32)(unsigned short)ls[0] | ((uint32)(unsigned short)ls[1] << 16);
        ol[rg].y = (uint32)(unsigned short)ls[2] | ((uint32)(unsigned short)ls[3] << 16);
    }
    __syncthreads();  // all waves done reading mean planes
#pragma unroll
    for (int rg = 0; rg < 4; rg++) {
        int idx = (4 * w + rg) * PSTR + m * 8 + 4 * hh;  // plane j>>3 = 4w+rg
        *(uint2*)&smH[idx] = oh[rg];
        *(uint2*)&smL[idx] = ol[rg];
    }
    __syncthreads();

    // GEMM2: B-fragments from LDS h planes, tile jt=w
#pragma unroll
    for (int r = 0; r < 16; r++) acc[r] = 0.f;
#pragma unroll
    for (int kc = 0; kc < 8; kc++) {
        int c = 2 * kc + hh;
        bf16x8 bH = *(const bf16x8*)&smH[c * PSTR + m * 8];
        bf16x8 bL = *(const bf16x8*)&smL[c * PSTR + m * 8];
        bf16x8 aH = *(const bf16x8*)(W2pH + c * 1024 + (32 * w + m) * 8);
        bf16x8 aL = *(const bf16x8*)(W2pL + c * 1024 + (32 * w + m) * 8);
        acc = __builtin_amdgcn_mfma_f32_32x32x16_bf16(aH, bH, acc, 0, 0, 0);
        acc = __builtin_amdgcn_mfma_f32_32x32x16_bf16(aL, bH, acc, 0, 0, 0);
        acc = __builtin_amdgcn_mfma_f32_32x32x16_bf16(aH, bL, acc, 0, 0, 0);
    }
    if (mynode >= N) return;
    if (w < 2) {
        // waves 0,1: cols 0..63 = h @ W2l^T -> hl (bf16)
#pragma unroll
        for (int rg = 0; rg < 4; rg++) {
            int j0 = 32 * w + 8 * rg + 4 * hh;
            uint2 o;
            o.x = pack_bf16_rne(acc[4 * rg + 0], acc[4 * rg + 1]);
            o.y = pack_bf16_rne(acc[4 * rg + 2], acc[4 * rg + 3]);
            *(uint2*)&hl[(size_t)mynode * 64 + j0] = o;
        }
    } else {
        // waves 2,3: cols 64..127 = h @ W2r^T + b2 -> hr (fp32)
#pragma unroll
        for (int rg = 0; rg < 4; rg++) {
            int j0 = 32 * (w - 2) + 8 * rg + 4 * hh;
            float4 bv = *(const float4*)(b2 + j0);
            float4 o;
            o.x = acc[4 * rg + 0] + bv.x;
            o.y = acc[4 * rg + 1] + bv.y;
            o.z = acc[4 * rg + 2] + bv.z;
            o.w = acc[4 * rg + 3] + bv.w;
            *(float4*)&hr[(size_t)mynode * 64 + j0] = o;
        }
    }
}

// ---- aggregation 2: gather from hl; pk-f32 accumulate; col prefetch ----

__global__ void k_agg_out(const int* __restrict__ rp, const int* __restrict__ col,
                          const uint32* __restrict__ hl, const float* __restrict__ hr,
                          float* __restrict__ out, int N) {
    int node = blockIdx.x * 4 + (threadIdx.x >> 6);
    if (node >= N) return;
    node = __builtin_amdgcn_readfirstlane(node);
    int lane = threadIdx.x & 63;
    int g = lane >> 3;
    int f = lane & 7;
    int beg = rp[node], end = rp[node + 1];
    const uint4* hl4 = (const uint4*)hl;  // row = 8 uint4
    f32x2 sA[4];
#pragma unroll
    for (int j = 0; j < 4; j++) sA[j] = (f32x2){0.f, 0.f};

#define ACC_MSK(v)                                          \
    { sA[0] += (f32x2){bf_lo(v.x), bf_hi(v.x)};             \
      sA[1] += (f32x2){bf_lo(v.y), bf_hi(v.y)};             \
      sA[2] += (f32x2){bf_lo(v.z), bf_hi(v.z)};             \
      sA[3] += (f32x2){bf_lo(v.w), bf_hi(v.w)}; }

    // 1-deep col prefetch; overshoot reads stay inside workspace and are
    // dereferenced only when the loop proves them in-segment.
    uint2 cv = *(const uint2*)(col + beg + 2 * g);
    int e = beg;
    for (; e + 16 <= end; e += 16) {
        uint2 cvn = *(const uint2*)(col + e + 16 + 2 * g);
        uint4 v0 = hl4[(size_t)cv.x * 8 + f];
        uint4 v1 = hl4[(size_t)cv.y * 8 + f];
        ACC_MSK(v0); ACC_MSK(v1);
        cv = cvn;
    }
    for (; e + 8 <= end; e += 8) {
        uint4 v0 = hl4[(size_t)col[e + g] * 8 + f];
        ACC_MSK(v0);
    }
    int rem = end - e;
    if (g < rem) {
        uint4 v0 = hl4[(size_t)col[e + g] * 8 + f];
        ACC_MSK(v0);
    }
#undef ACC_MSK
#pragma unroll
    for (int p = 0; p < 4; p++) {
        sA[p].x += __shfl_xor(sA[p].x, 8);
        sA[p].y += __shfl_xor(sA[p].y, 8);
        sA[p].x += __shfl_xor(sA[p].x, 16);
        sA[p].y += __shfl_xor(sA[p].y, 16);
        sA[p].x += __shfl_xor(sA[p].x, 32);
        sA[p].y += __shfl_xor(sA[p].y, 32);
    }
    if (g == 0) {
        float inv = 1.0f / (float)max(end - beg, 1);
        const float* hrp = hr + (size_t)node * 64 + f * 8;
        float4 h0 = *(const float4*)(hrp);
        float4 h1 = *(const float4*)(hrp + 4);
        float4 o0, o1;
        o0.x = sA[0].x * inv + h0.x;
        o0.y = sA[0].y * inv + h0.y;
        o0.z = sA[1].x * inv + h0.z;
        o0.w = sA[1].y * inv + h0.w;
        o1.x = sA[2].x * inv + h1.x;
        o1.y = sA[2].y * inv + h1.y;
        o1.z = sA[3].x * inv + h1.z;
        o1.w = sA[3].y * inv + h1.w;
        float* op = out + (size_t)node * 64 + f * 8;
        *(float4*)(op) = o0;
        *(float4*)(op + 4) = o1;
    }
}

extern "C" void kernel_launch(void* const* d_in, const int* in_sizes, int n_in,
                              void* d_out, int out_size, void* d_ws, size_t ws_size,
                              hipStream_t stream) {
    const float* x   = (const float*)d_in[0];
    const float* W1l = (const float*)d_in[1];
    const float* W1r = (const float*)d_in[2];
    const float* b1  = (const float*)d_in[3];
    const float* W2l = (const float*)d_in[4];
    const float* W2r = (const float*)d_in[5];
    const float* b2  = (const float*)d_in[6];
    const int*   ei  = (const int*)d_in[7];
    int N = in_sizes[0] / 128;
    int E = in_sizes[7] / 2;
    int NB = (N + 255) >> 8;   // 391 for N=100k (local scans assume <=512)
    int mb = (N + 31) / 32;
    int Np = ((N + 127) / 128) * 128;  // padded node count
    float* out = (float*)d_out;

    char* w = (char*)d_ws;
    size_t off = 0;
    auto alloc = [&](size_t bytes) -> char* {
        char* p = w + off;
        off += (bytes + 255) & ~(size_t)255;
        return p;
    };
    int*   row_ptr = (int*)alloc((size_t)(N + 1) * 4);
    int*   bwork   = (int*)alloc((size_t)2 * (NB + 1) * 4);  // bcnt | bcur
    short* W1pH    = (short*)alloc(32768 * 2);
    short* W1pL    = (short*)alloc(32768 * 2);
    short* W2pH    = (short*)alloc(16384 * 2);
    short* W2pL    = (short*)alloc(16384 * 2);
    int*   col     = (int*)alloc((size_t)E * 4);
    uint32* xb     = (uint32*)alloc((size_t)Np * 64 * 4);   // 25.6 MB
    float*  hr     = (float*)alloc((size_t)Np * 64 * 4);    // 25.6 MB
    unsigned short* hl = (unsigned short*)alloc((size_t)N * 64 * 2);  // 12.8 MB
    int* bcnt = bwork;
    int* bcur = bwork + (NB + 1);
    // alias (lifetime-disjoint): eb dead after k_bfinal; hl written by k_fused
    uint32* eb = (uint32*)hl;

    hipMemsetAsync(bwork, 0, (size_t)2 * (NB + 1) * 4, stream);
    long n4 = (long)N * 32;
    long prep_items = n4 + 32768 + 16384;
    int prep_blocks = (int)((prep_items + 255) / 256);
    k_prepcount<<<prep_blocks + 256, 256, 0, stream>>>(
        x, xb, n4, W1l, W1r, W2l, W2r, W1pH, W1pL, W2pH, W2pL,
        ei, E, NB, bcnt, prep_blocks);
    k_bscatter<<<128, 256, 0, stream>>>(ei, E, NB, bcnt, bcur, eb);
    k_bfinal<<<NB, 256, 0, stream>>>(eb, bcnt, row_ptr, col, N, E, NB);

    k_fused<<<mb, 256, 0, stream>>>(row_ptr, col, xb, W1pH, W1pL, W2pH, W2pL,
                                    b1, b2, hl, hr, N);
    int ab = (N + 3) / 4;
    k_agg_out<<<ab, 256, 0, stream>>>(row_ptr, col, (const uint32*)hl, hr, out, N);
}

// Round 7
// 323.029 us; speedup vs baseline: 1.0536x; 1.0536x over previous
//
#include <hip/hip_runtime.h>

// SAGE_Net: 2-layer GraphSAGE, N=100k, E=1.6M, 128->128->64, fp32.
// R16: revert R15's k_fused prefetch pipeline (VGPR 36->64, occ 64->36%,
// dur 102->121 -- wave count beats per-wave MLP here). Keep R15's
// consolidated CSR build (prep+bcount merged; bscan folded into local LDS
// scans in bscatter/bfinal). agg_out regrouped 8x8 -> 4x16 lanes: uint4
// col loads give 4 rows in flight per lane (was 2) at zero extra VGPR.

typedef unsigned int uint32;
typedef short bf16x4 __attribute__((ext_vector_type(4)));
typedef short bf16x8 __attribute__((ext_vector_type(8)));
typedef float f32x16 __attribute__((ext_vector_type(16)));
typedef float f32x2 __attribute__((ext_vector_type(2)));

#define PSTR 264  // LDS plane stride in shorts (32*8 + 8 pad; 528B)

__device__ __forceinline__ uint32 pack_bf16_rne(float a, float b) {
    uint32 ua = __float_as_uint(a);
    uint32 ub = __float_as_uint(b);
    uint32 ra = (ua + 0x7fffu + ((ua >> 16) & 1u)) >> 16;
    uint32 rb = (ub + 0x7fffu + ((ub >> 16) & 1u)) >> 16;
    return ra | (rb << 16);
}
__device__ __forceinline__ float bf_lo(uint32 v) { return __uint_as_float(v << 16); }
__device__ __forceinline__ float bf_hi(uint32 v) { return __uint_as_float(v & 0xffff0000u); }

__device__ __forceinline__ short rne16(float v, float* back) {
    uint32 u = __float_as_uint(v);
    uint32 r = (u + 0x7fffu + ((u >> 16) & 1u)) >> 16;
    *back = __uint_as_float(r << 16);
    return (short)r;
}

// ---- prep (x -> xb bf16; weights -> hi/lo planes) + bcount, one kernel ----
__global__ void k_prepcount(const float* __restrict__ x, uint32* __restrict__ xb,
                            long n4,
                            const float* __restrict__ W1l, const float* __restrict__ W1r,
                            const float* __restrict__ W2l, const float* __restrict__ W2r,
                            short* __restrict__ W1pH, short* __restrict__ W1pL,
                            short* __restrict__ W2pH, short* __restrict__ W2pL,
                            const int* __restrict__ ei, int E, int NB,
                            int* __restrict__ bucket_cnt, int prep_blocks) {
    __shared__ int hist[512];
    int t = threadIdx.x;
    if ((int)blockIdx.x >= prep_blocks) {
        // ---- bcount section (256 blocks) ----
        int bb = (int)blockIdx.x - prep_blocks;
        for (int i = t; i < NB; i += 256) hist[i] = 0;
        __syncthreads();
        int stride = 256 * 256;
        for (int e = bb * 256 + t; e < E; e += stride)
            atomicAdd(&hist[ei[E + e] >> 8], 1);
        __syncthreads();
        for (int i = t; i < NB; i += 256) {
            int c = hist[i];
            if (c) atomicAdd(&bucket_cnt[i], c);
        }
        return;
    }
    long i = (long)blockIdx.x * blockDim.x + t;
    float back;
    if (i < n4) {
        float4 v = ((const float4*)x)[i];
        short h0 = rne16(v.x, &back);
        short h1 = rne16(v.y, &back);
        short h2 = rne16(v.z, &back);
        short h3 = rne16(v.w, &back);
        uint2 o;
        o.x = (uint32)(unsigned short)h0 | ((uint32)(unsigned short)h1 << 16);
        o.y = (uint32)(unsigned short)h2 | ((uint32)(unsigned short)h3 << 16);
        ((uint2*)xb)[i] = o;
        return;
    }
    int i2 = (int)(i - n4);
    if (i2 < 32768) {
        int j = i2 >> 8, k = i2 & 255;
        float v = (k < 128) ? W1l[j * 128 + k] : W1r[j * 128 + k - 128];
        float hb;
        short hs = rne16(v, &hb);
        short ls = rne16(v - hb, &back);
        int idx = (k >> 3) * 1024 + j * 8 + (k & 7);
        W1pH[idx] = hs;
        W1pL[idx] = ls;
    } else if (i2 < 32768 + 16384) {
        int i3 = i2 - 32768;
        int j = i3 >> 7, k = i3 & 127;
        float v = (j < 64) ? W2l[j * 128 + k] : W2r[(j - 64) * 128 + k];
        float hb;
        short hs = rne16(v, &hb);
        short ls = rne16(v - hb, &back);
        int idx = (k >> 3) * 1024 + j * 8 + (k & 7);
        W2pH[idx] = hs;
        W2pL[idx] = ls;
    }
}

// ---- bscatter with local bucket scan (NB <= 512; this problem: 391) ----
__global__ void k_bscatter(const int* __restrict__ ei, int E, int NB,
                           const int* __restrict__ bcnt, int* __restrict__ bcur,
                           uint32* __restrict__ eb) {
    __shared__ int sc[512];
    __shared__ int hist[512];
    __shared__ int basev[512];
    int t = threadIdx.x;
    int c0 = (t < NB) ? bcnt[t] : 0;
    int c1 = (t + 256 < NB) ? bcnt[t + 256] : 0;
    sc[t] = c0;
    sc[t + 256] = c1;
    hist[t] = 0;
    hist[t + 256] = 0;
    __syncthreads();
    for (int o = 1; o < 512; o <<= 1) {
        int a0 = (t >= o) ? sc[t - o] : 0;
        int a1 = (t + 256 >= o) ? sc[t + 256 - o] : 0;
        __syncthreads();
        sc[t] += a0;
        sc[t + 256] += a1;
        __syncthreads();
    }
    int stride = gridDim.x * 256;
    for (int e = blockIdx.x * 256 + t; e < E; e += stride)
        atomicAdd(&hist[ei[E + e] >> 8], 1);
    __syncthreads();
    {
        int c = hist[t];
        if (t < NB) basev[t] = (sc[t] - c0) + (c ? atomicAdd(&bcur[t], c) : 0);
        hist[t] = 0;
        int i1 = t + 256;
        int c2 = hist[i1];
        if (i1 < NB) basev[i1] = (sc[i1] - c1) + (c2 ? atomicAdd(&bcur[i1], c2) : 0);
        hist[i1] = 0;
    }
    __syncthreads();
    for (int e = blockIdx.x * 256 + t; e < E; e += stride) {
        int d = ei[E + e];
        int b = d >> 8;
        int r = atomicAdd(&hist[b], 1);
        eb[basev[b] + r] = ((uint32)(d & 255) << 24) | (uint32)ei[e];
    }
}

// ---- bfinal with local bucket scan ----
__global__ void k_bfinal(const uint32* __restrict__ eb,
                         const int* __restrict__ bcnt,
                         int* __restrict__ row_ptr, int* __restrict__ col,
                         int N, int E, int NB) {
    __shared__ int sc[512];
    __shared__ int deg[256];
    __shared__ int scn[256];
    __shared__ int cur[256];
    int b = blockIdx.x;
    int t = threadIdx.x;
    sc[t] = (t < NB) ? bcnt[t] : 0;
    sc[t + 256] = (t + 256 < NB) ? bcnt[t + 256] : 0;
    deg[t] = 0;
    __syncthreads();
    for (int o = 1; o < 512; o <<= 1) {
        int a0 = (t >= o) ? sc[t - o] : 0;
        int a1 = (t + 256 >= o) ? sc[t + 256 - o] : 0;
        __syncthreads();
        sc[t] += a0;
        sc[t + 256] += a1;
        __syncthreads();
    }
    int beg = (b > 0) ? sc[b - 1] : 0;
    int end = sc[b];
    for (int e = beg + t; e < end; e += 256)
        atomicAdd(&deg[eb[e] >> 24], 1);
    __syncthreads();
    int v = deg[t];
    scn[t] = v;
    __syncthreads();
    for (int o = 1; o < 256; o <<= 1) {
        int u = (t >= o) ? scn[t - o] : 0;
        __syncthreads();
        scn[t] += u;
        __syncthreads();
    }
    int ex = scn[t] - v;
    int node = b * 256 + t;
    if (node < N) row_ptr[node] = beg + ex;
    if (b == gridDim.x - 1 && t == 0) row_ptr[N] = E;
    cur[t] = ex;
    __syncthreads();
    for (int e = beg + t; e < end; e += 256) {
        uint32 u = eb[e];
        int r = atomicAdd(&cur[u >> 24], 1);
        col[beg + r] = (int)(u & 0xFFFFFFu);
    }
}

// ---- fused gather-mean + 2x MFMA GEMM. Block = 32 nodes, 4 waves.
// Phase A restored to R14 exact form (36 VGPR, occ 64%, 102us measured). ----

__global__ __launch_bounds__(256, 4) void k_fused(
        const int* __restrict__ rp, const int* __restrict__ col,
        const uint32* __restrict__ xb,
        const short* __restrict__ W1pH, const short* __restrict__ W1pL,
        const short* __restrict__ W2pH, const short* __restrict__ W2pL,
        const float* __restrict__ b1, const float* __restrict__ b2,
        unsigned short* __restrict__ hl, float* __restrict__ hr, int N) {
    __shared__ short smH[16 * PSTR];  // mean hi planes; reused for h hi
    __shared__ short smL[16 * PSTR];  // mean lo planes; reused for h lo
    int t = threadIdx.x;
    int w = t >> 6, lane = t & 63;
    int g = lane >> 4, f = lane & 15;
    int node0 = blockIdx.x * 32;
    const uint4* xb4 = (const uint4*)xb;  // row = 16 uint4

    // phase A: gather-mean for 8 nodes/wave. rp prefetched via one load.
    int base = node0 + 8 * w;
    int rpi = base + lane;
    if (rpi > N) rpi = N;
    int rpv = rp[rpi];

    for (int i = 0; i < 8; i++) {
        int lr = 8 * w + i;
        int beg = __builtin_amdgcn_readfirstlane(__shfl(rpv, i));
        int end = __builtin_amdgcn_readfirstlane(__shfl(rpv, i + 1));
        f32x2 sA[4];
#pragma unroll
        for (int j = 0; j < 4; j++) sA[j] = (f32x2){0.f, 0.f};

        // packed (lo, raw-hi) accumulate -> v_pk_add_f32
#define ACC_RAW(v)                                                      \
    { sA[0] += (f32x2){bf_lo(v.x), __uint_as_float(v.x)};               \
      sA[1] += (f32x2){bf_lo(v.y), __uint_as_float(v.y)};               \
      sA[2] += (f32x2){bf_lo(v.z), __uint_as_float(v.z)};               \
      sA[3] += (f32x2){bf_lo(v.w), __uint_as_float(v.w)}; }

        int e = beg;
        for (; e + 16 <= end; e += 16) {
            uint4 cv = *(const uint4*)(col + e + 4 * g);
            uint4 v0 = xb4[(size_t)cv.x * 16 + f];
            uint4 v1 = xb4[(size_t)cv.y * 16 + f];
            uint4 v2 = xb4[(size_t)cv.z * 16 + f];
            uint4 v3 = xb4[(size_t)cv.w * 16 + f];
            ACC_RAW(v0); ACC_RAW(v1); ACC_RAW(v2); ACC_RAW(v3);
        }
        for (; e + 8 <= end; e += 8) {
            uint2 cv = *(const uint2*)(col + e + 2 * g);
            uint4 v0 = xb4[(size_t)cv.x * 16 + f];
            uint4 v1 = xb4[(size_t)cv.y * 16 + f];
            ACC_RAW(v0); ACC_RAW(v1);
        }
        int rem = end - e;
        if (2 * g < rem) {
            uint4 v0 = xb4[(size_t)col[e + 2 * g] * 16 + f];
            ACC_RAW(v0);
        }
        if (2 * g + 1 < rem) {
            uint4 v0 = xb4[(size_t)col[e + 2 * g + 1] * 16 + f];
            ACC_RAW(v0);
        }
#undef ACC_RAW
#pragma unroll
        for (int p = 0; p < 4; p++) {
            sA[p].x += __shfl_xor(sA[p].x, 16);
            sA[p].y += __shfl_xor(sA[p].y, 16);
            sA[p].x += __shfl_xor(sA[p].x, 32);
            sA[p].y += __shfl_xor(sA[p].y, 32);
        }
        // distributed epilogue: lane (g,f) -> plane f, features 2g,2g+1
        float inv = 1.0f / (float)max(end - beg, 1);
        float m0 = sA[g].x * inv, m1 = sA[g].y * inv;
        float b_;
        short h0 = rne16(m0, &b_);
        float bk0 = b_;
        short l0 = rne16(m0 - bk0, &b_);
        short h1 = rne16(m1, &b_);
        float bk1 = b_;
        short l1 = rne16(m1 - bk1, &b_);
        uint32 H = (uint32)(unsigned short)h0 | ((uint32)(unsigned short)h1 << 16);
        uint32 L = (uint32)(unsigned short)l0 | ((uint32)(unsigned short)l1 << 16);
        *(uint32*)&smH[f * PSTR + lr * 8 + 2 * g] = H;
        *(uint32*)&smL[f * PSTR + lr * 8 + 2 * g] = L;
    }
    __syncthreads();

    // phase B: GEMM1 (mean hi/lo from LDS + x hi direct from xb), tile jt=w
    int m = lane & 31, hh = lane >> 5;
    int mynode = node0 + m;
    const short* xbs = (const short*)xb;  // row = 128 shorts (feature order)
    f32x16 acc;
#pragma unroll
    for (int r = 0; r < 16; r++) acc[r] = 0.f;
#pragma unroll
    for (int kc = 0; kc < 8; kc++) {
        int c = 2 * kc + hh;
        bf16x8 bH = *(const bf16x8*)&smH[c * PSTR + m * 8];
        bf16x8 bL = *(const bf16x8*)&smL[c * PSTR + m * 8];
        bf16x8 xH = *(const bf16x8*)(xbs + (size_t)mynode * 128 + c * 8);
        bf16x8 aH1 = *(const bf16x8*)(W1pH + c * 1024 + (32 * w + m) * 8);
        bf16x8 aL1 = *(const bf16x8*)(W1pL + c * 1024 + (32 * w + m) * 8);
        bf16x8 aH2 = *(const bf16x8*)(W1pH + (16 + c) * 1024 + (32 * w + m) * 8);
        bf16x8 aL2 = *(const bf16x8*)(W1pL + (16 + c) * 1024 + (32 * w + m) * 8);
        acc = __builtin_amdgcn_mfma_f32_32x32x16_bf16(aH1, bH, acc, 0, 0, 0);
        acc = __builtin_amdgcn_mfma_f32_32x32x16_bf16(aL1, bH, acc, 0, 0, 0);
        acc = __builtin_amdgcn_mfma_f32_32x32x16_bf16(aH1, bL, acc, 0, 0, 0);
        acc = __builtin_amdgcn_mfma_f32_32x32x16_bf16(aH2, xH, acc, 0, 0, 0);
        acc = __builtin_amdgcn_mfma_f32_32x32x16_bf16(aL2, xH, acc, 0, 0, 0);
    }

    // epilogue 1: relu + b1 -> h (hi/lo) in regs
    uint2 oh[4], ol[4];
#pragma unroll
    for (int rg = 0; rg < 4; rg++) {
        int j0 = 32 * w + 8 * rg + 4 * hh;
        float4 bv = *(const float4*)(b1 + j0);
        float bb[4] = {bv.x, bv.y, bv.z, bv.w};
        short hs[4], ls[4];
#pragma unroll
        for (int q = 0; q < 4; q++) {
            float v = fmaxf(acc[4 * rg + q] + bb[q], 0.f);
            float back;
            hs[q] = rne16(v, &back);
            ls[q] = rne16(v - back, &back);
        }
        oh[rg].x = (uint32)(unsigned short)hs[0] | ((uint32)(unsigned short)hs[1] << 16);
        oh[rg].y = (uint32)(unsigned short)hs[2] | ((uint32)(unsigned short)hs[3] << 16);
        ol[rg].x = (uint32)(unsigned short)ls[0] | ((uint32)(unsigned short)ls[1] << 16);
        ol[rg].y = (uint32)(unsigned short)ls[2] | ((uint32)(unsigned short)ls[3] << 16);
    }
    __syncthreads();  // all waves done reading mean planes
#pragma unroll
    for (int rg = 0; rg < 4; rg++) {
        int idx = (4 * w + rg) * PSTR + m * 8 + 4 * hh;  // plane j>>3 = 4w+rg
        *(uint2*)&smH[idx] = oh[rg];
        *(uint2*)&smL[idx] = ol[rg];
    }
    __syncthreads();

    // GEMM2: B-fragments from LDS h planes, tile jt=w
#pragma unroll
    for (int r = 0; r < 16; r++) acc[r] = 0.f;
#pragma unroll
    for (int kc = 0; kc < 8; kc++) {
        int c = 2 * kc + hh;
        bf16x8 bH = *(const bf16x8*)&smH[c * PSTR + m * 8];
        bf16x8 bL = *(const bf16x8*)&smL[c * PSTR + m * 8];
        bf16x8 aH = *(const bf16x8*)(W2pH + c * 1024 + (32 * w + m) * 8);
        bf16x8 aL = *(const bf16x8*)(W2pL + c * 1024 + (32 * w + m) * 8);
        acc = __builtin_amdgcn_mfma_f32_32x32x16_bf16(aH, bH, acc, 0, 0, 0);
        acc = __builtin_amdgcn_mfma_f32_32x32x16_bf16(aL, bH, acc, 0, 0, 0);
        acc = __builtin_amdgcn_mfma_f32_32x32x16_bf16(aH, bL, acc, 0, 0, 0);
    }
    if (mynode >= N) return;
    if (w < 2) {
        // waves 0,1: cols 0..63 = h @ W2l^T -> hl (bf16)
#pragma unroll
        for (int rg = 0; rg < 4; rg++) {
            int j0 = 32 * w + 8 * rg + 4 * hh;
            uint2 o;
            o.x = pack_bf16_rne(acc[4 * rg + 0], acc[4 * rg + 1]);
            o.y = pack_bf16_rne(acc[4 * rg + 2], acc[4 * rg + 3]);
            *(uint2*)&hl[(size_t)mynode * 64 + j0] = o;
        }
    } else {
        // waves 2,3: cols 64..127 = h @ W2r^T + b2 -> hr (fp32)
#pragma unroll
        for (int rg = 0; rg < 4; rg++) {
            int j0 = 32 * (w - 2) + 8 * rg + 4 * hh;
            float4 bv = *(const float4*)(b2 + j0);
            float4 o;
            o.x = acc[4 * rg + 0] + bv.x;
            o.y = acc[4 * rg + 1] + bv.y;
            o.z = acc[4 * rg + 2] + bv.z;
            o.w = acc[4 * rg + 3] + bv.w;
            *(float4*)&hr[(size_t)mynode * 64 + j0] = o;
        }
    }
}

// ---- aggregation 2: gather from hl. R16: 4 groups x 16 lanes, uint2 row
// slices (8B/lane), uint4 col loads -> 4 rows in flight per lane (was 2)
// at zero extra VGPR. ----

__global__ void k_agg_out(const int* __restrict__ rp, const int* __restrict__ col,
                          const uint32* __restrict__ hl, const float* __restrict__ hr,
                          float* __restrict__ out, int N) {
    int node = blockIdx.x * 4 + (threadIdx.x >> 6);
    if (node >= N) return;
    node = __builtin_amdgcn_readfirstlane(node);
    int lane = threadIdx.x & 63;
    int g = lane >> 4;    // 4 groups
    int f = lane & 15;    // 16 lanes: features [4f, 4f+4)
    int beg = rp[node], end = rp[node + 1];
    const uint2* hl2 = (const uint2*)hl;  // row = 16 uint2 (128B)
    f32x2 sA[2];
    sA[0] = (f32x2){0.f, 0.f};
    sA[1] = (f32x2){0.f, 0.f};

#define ACC_MSK(v)                                          \
    { sA[0] += (f32x2){bf_lo(v.x), bf_hi(v.x)};             \
      sA[1] += (f32x2){bf_lo(v.y), bf_hi(v.y)}; }

    int e = beg;
    for (; e + 16 <= end; e += 16) {
        uint4 cv = *(const uint4*)(col + e + 4 * g);
        uint2 v0 = hl2[(size_t)cv.x * 16 + f];
        uint2 v1 = hl2[(size_t)cv.y * 16 + f];
        uint2 v2 = hl2[(size_t)cv.z * 16 + f];
        uint2 v3 = hl2[(size_t)cv.w * 16 + f];
        ACC_MSK(v0); ACC_MSK(v1); ACC_MSK(v2); ACC_MSK(v3);
    }
    for (; e + 4 <= end; e += 4) {
        uint2 v0 = hl2[(size_t)col[e + g] * 16 + f];
        ACC_MSK(v0);
    }
    int rem = end - e;
    if (g < rem) {
        uint2 v0 = hl2[(size_t)col[e + g] * 16 + f];
        ACC_MSK(v0);
    }
#undef ACC_MSK
#pragma unroll
    for (int p = 0; p < 2; p++) {
        sA[p].x += __shfl_xor(sA[p].x, 16);
        sA[p].y += __shfl_xor(sA[p].y, 16);
        sA[p].x += __shfl_xor(sA[p].x, 32);
        sA[p].y += __shfl_xor(sA[p].y, 32);
    }
    if (g == 0) {
        float inv = 1.0f / (float)max(end - beg, 1);
        const float* hrp = hr + (size_t)node * 64 + f * 4;
        float4 h0 = *(const float4*)(hrp);
        float4 o0;
        o0.x = sA[0].x * inv + h0.x;
        o0.y = sA[0].y * inv + h0.y;
        o0.z = sA[1].x * inv + h0.z;
        o0.w = sA[1].y * inv + h0.w;
        float* op = out + (size_t)node * 64 + f * 4;
        *(float4*)(op) = o0;
    }
}

extern "C" void kernel_launch(void* const* d_in, const int* in_sizes, int n_in,
                              void* d_out, int out_size, void* d_ws, size_t ws_size,
                              hipStream_t stream) {
    const float* x   = (const float*)d_in[0];
    const float* W1l = (const float*)d_in[1];
    const float* W1r = (const float*)d_in[2];
    const float* b1  = (const float*)d_in[3];
    const float* W2l = (const float*)d_in[4];
    const float* W2r = (const float*)d_in[5];
    const float* b2  = (const float*)d_in[6];
    const int*   ei  = (const int*)d_in[7];
    int N = in_sizes[0] / 128;
    int E = in_sizes[7] / 2;
    int NB = (N + 255) >> 8;   // 391 for N=100k (local scans assume <=512)
    int mb = (N + 31) / 32;
    int Np = ((N + 127) / 128) * 128;  // padded node count
    float* out = (float*)d_out;

    char* w = (char*)d_ws;
    size_t off = 0;
    auto alloc = [&](size_t bytes) -> char* {
        char* p = w + off;
        off += (bytes + 255) & ~(size_t)255;
        return p;
    };
    int*   row_ptr = (int*)alloc((size_t)(N + 1) * 4);
    int*   bwork   = (int*)alloc((size_t)2 * (NB + 1) * 4);  // bcnt | bcur
    short* W1pH    = (short*)alloc(32768 * 2);
    short* W1pL    = (short*)alloc(32768 * 2);
    short* W2pH    = (short*)alloc(16384 * 2);
    short* W2pL    = (short*)alloc(16384 * 2);
    int*   col     = (int*)alloc((size_t)E * 4);
    uint32* xb     = (uint32*)alloc((size_t)Np * 64 * 4);   // 25.6 MB
    float*  hr     = (float*)alloc((size_t)Np * 64 * 4);    // 25.6 MB
    unsigned short* hl = (unsigned short*)alloc((size_t)N * 64 * 2);  // 12.8 MB
    int* bcnt = bwork;
    int* bcur = bwork + (NB + 1);
    // alias (lifetime-disjoint): eb dead after k_bfinal; hl written by k_fused
    uint32* eb = (uint32*)hl;

    hipMemsetAsync(bwork, 0, (size_t)2 * (NB + 1) * 4, stream);
    long n4 = (long)N * 32;
    long prep_items = n4 + 32768 + 16384;
    int prep_blocks = (int)((prep_items + 255) / 256);
    k_prepcount<<<prep_blocks + 256, 256, 0, stream>>>(
        x, xb, n4, W1l, W1r, W2l, W2r, W1pH, W1pL, W2pH, W2pL,
        ei, E, NB, bcnt, prep_blocks);
    k_bscatter<<<128, 256, 0, stream>>>(ei, E, NB, bcnt, bcur, eb);
    k_bfinal<<<NB, 256, 0, stream>>>(eb, bcnt, row_ptr, col, N, E, NB);

    k_fused<<<mb, 256, 0, stream>>>(row_ptr, col, xb, W1pH, W1pL, W2pH, W2pL,
                                    b1, b2, hl, hr, N);
    int ab = (N + 3) / 4;
    k_agg_out<<<ab, 256, 0, stream>>>(row_ptr, col, (const uint32*)hl, hr, out, N);
}

// Round 8
// 318.667 us; speedup vs baseline: 1.0681x; 1.0137x over previous
//
#include <hip/hip_runtime.h>

// SAGE_Net: 2-layer GraphSAGE, N=100k, E=1.6M, 128->128->64, fp32.
// R17: (a) CSR build reverted to R14's separate kernels (R16's consolidated
// build measured +6us net). (b) NEW gather layout in k_fused phase A and
// k_agg_out: lane owns a feature (pair) -> one coalesced row load per edge,
// scalar col loads, NO cross-lane reduce (was 16+ instr/node), accumulate =
// 1 shift + 1 v_pk_add_f32 per edge. VGPR-neutral (R15 lesson: occupancy
// beats per-wave tricks). Per-edge arithmetic bit-identical; only fp32 sum
// order changes.

typedef unsigned int uint32;
typedef short bf16x8 __attribute__((ext_vector_type(8)));
typedef float f32x16 __attribute__((ext_vector_type(16)));
typedef float f32x2 __attribute__((ext_vector_type(2)));

#define PSTR 264  // LDS plane stride in shorts (32*8 + 8 pad; 528B)

__device__ __forceinline__ uint32 pack_bf16_rne(float a, float b) {
    uint32 ua = __float_as_uint(a);
    uint32 ub = __float_as_uint(b);
    uint32 ra = (ua + 0x7fffu + ((ua >> 16) & 1u)) >> 16;
    uint32 rb = (ub + 0x7fffu + ((ub >> 16) & 1u)) >> 16;
    return ra | (rb << 16);
}
__device__ __forceinline__ float bf_lo(uint32 v) { return __uint_as_float(v << 16); }

__device__ __forceinline__ short rne16(float v, float* back) {
    uint32 u = __float_as_uint(v);
    uint32 r = (u + 0x7fffu + ((u >> 16) & 1u)) >> 16;
    *back = __uint_as_float(r << 16);
    return (short)r;
}

// ---- prep: x -> xb (row-major packed bf16); weights -> hi/lo planes ----
__global__ void k_prep(const float* __restrict__ x, uint32* __restrict__ xb,
                       long n4,
                       const float* __restrict__ W1l, const float* __restrict__ W1r,
                       const float* __restrict__ W2l, const float* __restrict__ W2r,
                       short* __restrict__ W1pH, short* __restrict__ W1pL,
                       short* __restrict__ W2pH, short* __restrict__ W2pL) {
    long i = (long)blockIdx.x * blockDim.x + threadIdx.x;
    float back;
    if (i < n4) {
        float4 v = ((const float4*)x)[i];
        short h0 = rne16(v.x, &back);
        short h1 = rne16(v.y, &back);
        short h2 = rne16(v.z, &back);
        short h3 = rne16(v.w, &back);
        uint2 o;
        o.x = (uint32)(unsigned short)h0 | ((uint32)(unsigned short)h1 << 16);
        o.y = (uint32)(unsigned short)h2 | ((uint32)(unsigned short)h3 << 16);
        ((uint2*)xb)[i] = o;
        return;
    }
    int i2 = (int)(i - n4);
    if (i2 < 32768) {
        int j = i2 >> 8, k = i2 & 255;
        float v = (k < 128) ? W1l[j * 128 + k] : W1r[j * 128 + k - 128];
        float hb;
        short hs = rne16(v, &hb);
        short ls = rne16(v - hb, &back);
        int idx = (k >> 3) * 1024 + j * 8 + (k & 7);
        W1pH[idx] = hs;
        W1pL[idx] = ls;
    } else if (i2 < 32768 + 16384) {
        int i3 = i2 - 32768;
        int j = i3 >> 7, k = i3 & 127;
        float v = (j < 64) ? W2l[j * 128 + k] : W2r[(j - 64) * 128 + k];
        float hb;
        short hs = rne16(v, &hb);
        short ls = rne16(v - hb, &back);
        int idx = (k >> 3) * 1024 + j * 8 + (k & 7);
        W2pH[idx] = hs;
        W2pL[idx] = ls;
    }
}

// ---- bucketed CSR build (R14 form) ----

__global__ void k_bcount(const int* __restrict__ ei, int E, int NB,
                         int* __restrict__ bucket_cnt) {
    __shared__ int hist[1024];
    int t = threadIdx.x;
    for (int i = t; i < NB; i += 256) hist[i] = 0;
    __syncthreads();
    int stride = gridDim.x * 256;
    for (int e = blockIdx.x * 256 + t; e < E; e += stride)
        atomicAdd(&hist[ei[E + e] >> 8], 1);
    __syncthreads();
    for (int i = t; i < NB; i += 256) {
        int c = hist[i];
        if (c) atomicAdd(&bucket_cnt[i], c);
    }
}

__global__ void k_bscan(const int* __restrict__ bucket_cnt, int NB, int E,
                        int* __restrict__ bucket_off, int* __restrict__ bucket_cur) {
    __shared__ int s[1024];
    int t = threadIdx.x;
    int v = (t < NB) ? bucket_cnt[t] : 0;
    s[t] = v;
    __syncthreads();
    for (int o = 1; o < 1024; o <<= 1) {
        int u = (t >= o) ? s[t - o] : 0;
        __syncthreads();
        s[t] += u;
        __syncthreads();
    }
    int ex = s[t] - v;
    if (t < NB) { bucket_off[t] = ex; bucket_cur[t] = ex; }
    if (t == NB - 1) bucket_off[NB] = ex + v;
}

__global__ void k_bscatter(const int* __restrict__ ei, int E, int NB,
                           int* __restrict__ bucket_cur, uint32* __restrict__ eb) {
    __shared__ int hist[1024];
    __shared__ int base[1024];
    int t = threadIdx.x;
    for (int i = t; i < NB; i += 256) hist[i] = 0;
    __syncthreads();
    int stride = gridDim.x * 256;
    for (int e = blockIdx.x * 256 + t; e < E; e += stride)
        atomicAdd(&hist[ei[E + e] >> 8], 1);
    __syncthreads();
    for (int i = t; i < NB; i += 256) {
        int c = hist[i];
        base[i] = c ? atomicAdd(&bucket_cur[i], c) : 0;
        hist[i] = 0;
    }
    __syncthreads();
    for (int e = blockIdx.x * 256 + t; e < E; e += stride) {
        int d = ei[E + e];
        int b = d >> 8;
        int r = atomicAdd(&hist[b], 1);
        eb[base[b] + r] = ((uint32)(d & 255) << 24) | (uint32)ei[e];
    }
}

__global__ void k_bfinal(const uint32* __restrict__ eb,
                         const int* __restrict__ bucket_off,
                         int* __restrict__ row_ptr, int* __restrict__ col,
                         int N, int E) {
    __shared__ int deg[256];
    __shared__ int sc[256];
    __shared__ int cur[256];
    int b = blockIdx.x;
    int t = threadIdx.x;
    int beg = bucket_off[b], end = bucket_off[b + 1];
    deg[t] = 0;
    __syncthreads();
    for (int e = beg + t; e < end; e += 256)
        atomicAdd(&deg[eb[e] >> 24], 1);
    __syncthreads();
    int v = deg[t];
    sc[t] = v;
    __syncthreads();
    for (int o = 1; o < 256; o <<= 1) {
        int u = (t >= o) ? sc[t - o] : 0;
        __syncthreads();
        sc[t] += u;
        __syncthreads();
    }
    int ex = sc[t] - v;
    int node = b * 256 + t;
    if (node < N) row_ptr[node] = beg + ex;
    if (b == gridDim.x - 1 && t == 0) row_ptr[N] = E;
    cur[t] = ex;
    __syncthreads();
    for (int e = beg + t; e < end; e += 256) {
        uint32 u = eb[e];
        int r = atomicAdd(&cur[u >> 24], 1);
        col[beg + r] = (int)(u & 0xFFFFFFu);
    }
}

// ---- fused gather-mean + 2x MFMA GEMM. Block = 32 nodes, 4 waves.
// Phase A (R17): lane l owns features (2l, 2l+1). One dword row-load per
// edge (64x4B = full 256B row, coalesced), scalar col loads, NO reduce.
// Accumulate = 1 shift + 1 v_pk_add_f32 per edge. LDS plane write covers
// the same layout as before bit-identically. ----

__global__ __launch_bounds__(256, 4) void k_fused(
        const int* __restrict__ rp, const int* __restrict__ col,
        const uint32* __restrict__ xb,
        const short* __restrict__ W1pH, const short* __restrict__ W1pL,
        const short* __restrict__ W2pH, const short* __restrict__ W2pL,
        const float* __restrict__ b1, const float* __restrict__ b2,
        unsigned short* __restrict__ hl, float* __restrict__ hr, int N) {
    __shared__ short smH[16 * PSTR];  // mean hi planes; reused for h hi
    __shared__ short smL[16 * PSTR];  // mean lo planes; reused for h lo
    int t = threadIdx.x;
    int w = t >> 6, lane = t & 63;
    int node0 = blockIdx.x * 32;

    // phase A: gather-mean for 8 nodes/wave. rp prefetched via one load.
    int base = node0 + 8 * w;
    int rpi = base + lane;
    if (rpi > N) rpi = N;
    int rpv = rp[rpi];

#define ACC1(a) { s += (f32x2){bf_lo(a), __uint_as_float(a)}; }

    for (int i = 0; i < 8; i++) {
        int lr = 8 * w + i;
        int beg = __builtin_amdgcn_readfirstlane(__shfl(rpv, i));
        int end = __builtin_amdgcn_readfirstlane(__shfl(rpv, i + 1));
        f32x2 s = (f32x2){0.f, 0.f};
        int e = beg;
        for (; e + 8 <= end; e += 8) {
            int c0 = col[e + 0], c1 = col[e + 1], c2 = col[e + 2], c3 = col[e + 3];
            int c4 = col[e + 4], c5 = col[e + 5], c6 = col[e + 6], c7 = col[e + 7];
            uint32 a0 = xb[(size_t)c0 * 64 + lane];
            uint32 a1 = xb[(size_t)c1 * 64 + lane];
            uint32 a2 = xb[(size_t)c2 * 64 + lane];
            uint32 a3 = xb[(size_t)c3 * 64 + lane];
            uint32 a4 = xb[(size_t)c4 * 64 + lane];
            uint32 a5 = xb[(size_t)c5 * 64 + lane];
            uint32 a6 = xb[(size_t)c6 * 64 + lane];
            uint32 a7 = xb[(size_t)c7 * 64 + lane];
            ACC1(a0); ACC1(a1); ACC1(a2); ACC1(a3);
            ACC1(a4); ACC1(a5); ACC1(a6); ACC1(a7);
        }
        for (; e + 4 <= end; e += 4) {
            int c0 = col[e + 0], c1 = col[e + 1], c2 = col[e + 2], c3 = col[e + 3];
            uint32 a0 = xb[(size_t)c0 * 64 + lane];
            uint32 a1 = xb[(size_t)c1 * 64 + lane];
            uint32 a2 = xb[(size_t)c2 * 64 + lane];
            uint32 a3 = xb[(size_t)c3 * 64 + lane];
            ACC1(a0); ACC1(a1); ACC1(a2); ACC1(a3);
        }
        for (; e < end; e++) {
            uint32 a0 = xb[(size_t)col[e] * 64 + lane];
            ACC1(a0);
        }
        // epilogue: lane l -> plane l>>2, node lr, shorts 2(l&3)..+1
        float inv = 1.0f / (float)max(end - beg, 1);
        float m0 = s.x * inv, m1 = s.y * inv;
        float b_;
        short h0 = rne16(m0, &b_);
        float bk0 = b_;
        short l0 = rne16(m0 - bk0, &b_);
        short h1 = rne16(m1, &b_);
        float bk1 = b_;
        short l1 = rne16(m1 - bk1, &b_);
        uint32 H = (uint32)(unsigned short)h0 | ((uint32)(unsigned short)h1 << 16);
        uint32 L = (uint32)(unsigned short)l0 | ((uint32)(unsigned short)l1 << 16);
        int idx = (lane >> 2) * PSTR + lr * 8 + 2 * (lane & 3);
        *(uint32*)&smH[idx] = H;
        *(uint32*)&smL[idx] = L;
    }
#undef ACC1
    __syncthreads();

    // phase B: GEMM1 (mean hi/lo from LDS + x hi direct from xb), tile jt=w
    int m = lane & 31, hh = lane >> 5;
    int mynode = node0 + m;
    const short* xbs = (const short*)xb;  // row = 128 shorts (feature order)
    f32x16 acc;
#pragma unroll
    for (int r = 0; r < 16; r++) acc[r] = 0.f;
#pragma unroll
    for (int kc = 0; kc < 8; kc++) {
        int c = 2 * kc + hh;
        bf16x8 bH = *(const bf16x8*)&smH[c * PSTR + m * 8];
        bf16x8 bL = *(const bf16x8*)&smL[c * PSTR + m * 8];
        bf16x8 xH = *(const bf16x8*)(xbs + (size_t)mynode * 128 + c * 8);
        bf16x8 aH1 = *(const bf16x8*)(W1pH + c * 1024 + (32 * w + m) * 8);
        bf16x8 aL1 = *(const bf16x8*)(W1pL + c * 1024 + (32 * w + m) * 8);
        bf16x8 aH2 = *(const bf16x8*)(W1pH + (16 + c) * 1024 + (32 * w + m) * 8);
        bf16x8 aL2 = *(const bf16x8*)(W1pL + (16 + c) * 1024 + (32 * w + m) * 8);
        acc = __builtin_amdgcn_mfma_f32_32x32x16_bf16(aH1, bH, acc, 0, 0, 0);
        acc = __builtin_amdgcn_mfma_f32_32x32x16_bf16(aL1, bH, acc, 0, 0, 0);
        acc = __builtin_amdgcn_mfma_f32_32x32x16_bf16(aH1, bL, acc, 0, 0, 0);
        acc = __builtin_amdgcn_mfma_f32_32x32x16_bf16(aH2, xH, acc, 0, 0, 0);
        acc = __builtin_amdgcn_mfma_f32_32x32x16_bf16(aL2, xH, acc, 0, 0, 0);
    }

    // epilogue 1: relu + b1 -> h (hi/lo) in regs
    uint2 oh[4], ol[4];
#pragma unroll
    for (int rg = 0; rg < 4; rg++) {
        int j0 = 32 * w + 8 * rg + 4 * hh;
        float4 bv = *(const float4*)(b1 + j0);
        float bb[4] = {bv.x, bv.y, bv.z, bv.w};
        short hs[4], ls[4];
#pragma unroll
        for (int q = 0; q < 4; q++) {
            float v = fmaxf(acc[4 * rg + q] + bb[q], 0.f);
            float back;
            hs[q] = rne16(v, &back);
            ls[q] = rne16(v - back, &back);
        }
        oh[rg].x = (uint32)(unsigned short)hs[0] | ((uint32)(unsigned short)hs[1] << 16);
        oh[rg].y = (uint32)(unsigned short)hs[2] | ((uint32)(unsigned short)hs[3] << 16);
        ol[rg].x = (uint32)(unsigned short)ls[0] | ((uint32)(unsigned short)ls[1] << 16);
        ol[rg].y = (uint32)(unsigned short)ls[2] | ((uint32)(unsigned short)ls[3] << 16);
    }
    __syncthreads();  // all waves done reading mean planes
#pragma unroll
    for (int rg = 0; rg < 4; rg++) {
        int idx = (4 * w + rg) * PSTR + m * 8 + 4 * hh;  // plane j>>3 = 4w+rg
        *(uint2*)&smH[idx] = oh[rg];
        *(uint2*)&smL[idx] = ol[rg];
    }
    __syncthreads();

    // GEMM2: B-fragments from LDS h planes, tile jt=w
#pragma unroll
    for (int r = 0; r < 16; r++) acc[r] = 0.f;
#pragma unroll
    for (int kc = 0; kc < 8; kc++) {
        int c = 2 * kc + hh;
        bf16x8 bH = *(const bf16x8*)&smH[c * PSTR + m * 8];
        bf16x8 bL = *(const bf16x8*)&smL[c * PSTR + m * 8];
        bf16x8 aH = *(const bf16x8*)(W2pH + c * 1024 + (32 * w + m) * 8);
        bf16x8 aL = *(const bf16x8*)(W2pL + c * 1024 + (32 * w + m) * 8);
        acc = __builtin_amdgcn_mfma_f32_32x32x16_bf16(aH, bH, acc, 0, 0, 0);
        acc = __builtin_amdgcn_mfma_f32_32x32x16_bf16(aL, bH, acc, 0, 0, 0);
        acc = __builtin_amdgcn_mfma_f32_32x32x16_bf16(aH, bL, acc, 0, 0, 0);
    }
    if (mynode >= N) return;
    if (w < 2) {
        // waves 0,1: cols 0..63 = h @ W2l^T -> hl (bf16)
#pragma unroll
        for (int rg = 0; rg < 4; rg++) {
            int j0 = 32 * w + 8 * rg + 4 * hh;
            uint2 o;
            o.x = pack_bf16_rne(acc[4 * rg + 0], acc[4 * rg + 1]);
            o.y = pack_bf16_rne(acc[4 * rg + 2], acc[4 * rg + 3]);
            *(uint2*)&hl[(size_t)mynode * 64 + j0] = o;
        }
    } else {
        // waves 2,3: cols 64..127 = h @ W2r^T + b2 -> hr (fp32)
#pragma unroll
        for (int rg = 0; rg < 4; rg++) {
            int j0 = 32 * (w - 2) + 8 * rg + 4 * hh;
            float4 bv = *(const float4*)(b2 + j0);
            float4 o;
            o.x = acc[4 * rg + 0] + bv.x;
            o.y = acc[4 * rg + 1] + bv.y;
            o.z = acc[4 * rg + 2] + bv.z;
            o.w = acc[4 * rg + 3] + bv.w;
            *(float4*)&hr[(size_t)mynode * 64 + j0] = o;
        }
    }
}

// ---- aggregation 2 (R17): wave per node, lane l = feature l. One ushort
// row-load per edge (64x2B = full 128B row, coalesced), scalar col loads,
// no reduce; epilogue is one coalesced 256B row write. ----

__global__ void k_agg_out(const int* __restrict__ rp, const int* __restrict__ col,
                          const unsigned short* __restrict__ hl,
                          const float* __restrict__ hr,
                          float* __restrict__ out, int N) {
    int node = blockIdx.x * 4 + (threadIdx.x >> 6);
    if (node >= N) return;
    node = __builtin_amdgcn_readfirstlane(node);
    int lane = threadIdx.x & 63;
    int beg = rp[node], end = rp[node + 1];
    float s = 0.f;

#define ACCU(a) { s += __uint_as_float((uint32)(a) << 16); }

    int e = beg;
    for (; e + 8 <= end; e += 8) {
        int c0 = col[e + 0], c1 = col[e + 1], c2 = col[e + 2], c3 = col[e + 3];
        int c4 = col[e + 4], c5 = col[e + 5], c6 = col[e + 6], c7 = col[e + 7];
        unsigned short a0 = hl[(size_t)c0 * 64 + lane];
        unsigned short a1 = hl[(size_t)c1 * 64 + lane];
        unsigned short a2 = hl[(size_t)c2 * 64 + lane];
        unsigned short a3 = hl[(size_t)c3 * 64 + lane];
        unsigned short a4 = hl[(size_t)c4 * 64 + lane];
        unsigned short a5 = hl[(size_t)c5 * 64 + lane];
        unsigned short a6 = hl[(size_t)c6 * 64 + lane];
        unsigned short a7 = hl[(size_t)c7 * 64 + lane];
        ACCU(a0); ACCU(a1); ACCU(a2); ACCU(a3);
        ACCU(a4); ACCU(a5); ACCU(a6); ACCU(a7);
    }
    for (; e + 4 <= end; e += 4) {
        int c0 = col[e + 0], c1 = col[e + 1], c2 = col[e + 2], c3 = col[e + 3];
        unsigned short a0 = hl[(size_t)c0 * 64 + lane];
        unsigned short a1 = hl[(size_t)c1 * 64 + lane];
        unsigned short a2 = hl[(size_t)c2 * 64 + lane];
        unsigned short a3 = hl[(size_t)c3 * 64 + lane];
        ACCU(a0); ACCU(a1); ACCU(a2); ACCU(a3);
    }
    for (; e < end; e++) {
        unsigned short a0 = hl[(size_t)col[e] * 64 + lane];
        ACCU(a0);
    }
#undef ACCU
    float inv = 1.0f / (float)max(end - beg, 1);
    out[(size_t)node * 64 + lane] = s * inv + hr[(size_t)node * 64 + lane];
}

extern "C" void kernel_launch(void* const* d_in, const int* in_sizes, int n_in,
                              void* d_out, int out_size, void* d_ws, size_t ws_size,
                              hipStream_t stream) {
    const float* x   = (const float*)d_in[0];
    const float* W1l = (const float*)d_in[1];
    const float* W1r = (const float*)d_in[2];
    const float* b1  = (const float*)d_in[3];
    const float* W2l = (const float*)d_in[4];
    const float* W2r = (const float*)d_in[5];
    const float* b2  = (const float*)d_in[6];
    const int*   ei  = (const int*)d_in[7];
    int N = in_sizes[0] / 128;
    int E = in_sizes[7] / 2;
    int NB = (N + 255) >> 8;
    int mb = (N + 31) / 32;
    int Np = ((N + 127) / 128) * 128;  // padded node count
    float* out = (float*)d_out;

    char* w = (char*)d_ws;
    size_t off = 0;
    auto alloc = [&](size_t bytes) -> char* {
        char* p = w + off;
        off += (bytes + 255) & ~(size_t)255;
        return p;
    };
    int*   row_ptr = (int*)alloc((size_t)(N + 1) * 4);
    int*   bcnt    = (int*)alloc((size_t)(NB + 1) * 4);
    int*   boff    = (int*)alloc((size_t)(NB + 1) * 4);
    int*   bcur    = (int*)alloc((size_t)(NB + 1) * 4);
    short* W1pH    = (short*)alloc(32768 * 2);
    short* W1pL    = (short*)alloc(32768 * 2);
    short* W2pH    = (short*)alloc(16384 * 2);
    short* W2pL    = (short*)alloc(16384 * 2);
    int*   col     = (int*)alloc((size_t)E * 4);
    uint32* xb     = (uint32*)alloc((size_t)Np * 64 * 4);   // 25.6 MB
    float*  hr     = (float*)alloc((size_t)Np * 64 * 4);    // 25.6 MB
    unsigned short* hl = (unsigned short*)alloc((size_t)N * 64 * 2);  // 12.8 MB
    // alias (lifetime-disjoint): eb dead after k_bfinal; hl written by k_fused
    uint32* eb = (uint32*)hl;

    hipMemsetAsync(bcnt, 0, (size_t)NB * 4, stream);
    long n4 = (long)N * 32;
    long prep_items = n4 + 32768 + 16384;
    k_prep<<<(int)((prep_items + 255) / 256), 256, 0, stream>>>(
        x, xb, n4, W1l, W1r, W2l, W2r, W1pH, W1pL, W2pH, W2pL);
    k_bcount<<<256, 256, 0, stream>>>(ei, E, NB, bcnt);
    k_bscan<<<1, 1024, 0, stream>>>(bcnt, NB, E, boff, bcur);
    k_bscatter<<<128, 256, 0, stream>>>(ei, E, NB, bcur, eb);
    k_bfinal<<<NB, 256, 0, stream>>>(eb, boff, row_ptr, col, N, E);

    k_fused<<<mb, 256, 0, stream>>>(row_ptr, col, xb, W1pH, W1pL, W2pH, W2pL,
                                    b1, b2, hl, hr, N);
    int ab = (N + 3) / 4;
    k_agg_out<<<ab, 256, 0, stream>>>(row_ptr, col, hl, hr, out, N);
}